// Round 2
// baseline (1340.727 us; speedup 1.0000x reference)
//
#include <hip/hip_runtime.h>
#include <math.h>

static constexpr int NN = 50000;   // nodes
static constexpr int EE = 800000;  // edges

// ---------------- threefry2x32 (exact JAX semantics) ----------------
struct TF2 { unsigned a, b; };

__host__ __device__ __forceinline__ TF2 tf2x32(unsigned k0, unsigned k1,
                                               unsigned x0, unsigned x1) {
  unsigned k2 = k0 ^ k1 ^ 0x1BD11BDAu;
  x0 += k0; x1 += k1;
#define TFR(r) { x0 += x1; x1 = (x1 << (r)) | (x1 >> (32 - (r))); x1 ^= x0; }
  TFR(13) TFR(15) TFR(26) TFR(6)
  x0 += k1; x1 += k2 + 1u;
  TFR(17) TFR(29) TFR(16) TFR(24)
  x0 += k2; x1 += k0 + 2u;
  TFR(13) TFR(15) TFR(26) TFR(6)
  x0 += k0; x1 += k1 + 3u;
  TFR(17) TFR(29) TFR(16) TFR(24)
  x0 += k1; x1 += k2 + 4u;
  TFR(13) TFR(15) TFR(26) TFR(6)
  x0 += k2; x1 += k0 + 5u;
#undef TFR
  TF2 r; r.a = x0; r.b = x1; return r;
}

__device__ __forceinline__ float u01_bits(unsigned w) {
  // JAX uniform: bitcast((bits>>9)|0x3f800000) - 1; *(1-1e-20)==*1.0; +1e-20; max(1e-20,.)
  float fl = __uint_as_float((w >> 9) | 0x3f800000u) - 1.0f;
  return fmaxf(1e-20f, fl + 1e-20f);
}

// Forward value of gumbel straight-through = one_hot(argmax(softmax(z))).
// JAX >=0.4.30 default: threefry_partitionable=True ->
//   bits[f] = TF(key, (0, f)).a ^ TF(key, (0, f)).b   (64-bit counter = flat idx, XOR-fold)
__device__ __forceinline__ float keep01(float l0, float l1, unsigned k0, unsigned k1, int node) {
  unsigned f0 = 2u * (unsigned)node, f1 = f0 + 1u;
  TF2 t0 = tf2x32(k0, k1, 0u, f0);
  TF2 t1 = tf2x32(k0, k1, 0u, f1);
  float g0 = -logf(-logf(u01_bits(t0.a ^ t0.b)));
  float g1 = -logf(-logf(u01_bits(t1.a ^ t1.b)));
  float z0 = l0 + g0, z1 = l1 + g1;   // tau == 1
  float m  = fmaxf(z0, z1);
  float e0 = expf(z0 - m), e1 = expf(z1 - m);
  float s  = e0 + e1;
  float y0 = e0 / s, y1 = e1 / s;
  return (y1 > y0) ? 0.0f : 1.0f;     // argmax==0 -> keep (ties -> class 0, like jnp.argmax)
}

// ---------------- CSR build (dst-indexed, deterministic) ----------------
__global__ void k_count(const int* __restrict__ dst, int* __restrict__ deg, int e) {
  int i = blockIdx.x * blockDim.x + threadIdx.x;
  if (i < e) atomicAdd(&deg[dst[i]], 1);
}

__global__ void k_scan(const int* __restrict__ deg, int* __restrict__ row_ptr,
                       int* __restrict__ cursor, int n) {
  __shared__ int sums[1024];
  const int T = 1024;
  int t = threadIdx.x;
  int chunk = (n + T - 1) / T;
  int begin = t * chunk;
  int end   = begin + chunk; if (end > n) end = n;
  int s = 0;
  for (int i = begin; i < end; i++) s += deg[i];
  sums[t] = s;
  __syncthreads();
  for (int off = 1; off < T; off <<= 1) {
    int v = (t >= off) ? sums[t - off] : 0;
    __syncthreads();
    sums[t] += v;
    __syncthreads();
  }
  int run = (t == 0) ? 0 : sums[t - 1];
  for (int i = begin; i < end; i++) {
    row_ptr[i] = run; cursor[i] = run;
    run += deg[i];
  }
  if (t == T - 1) row_ptr[n] = run;
}

__global__ void k_fill(const int* __restrict__ src, const int* __restrict__ dst,
                       int* __restrict__ cursor, int* __restrict__ col, int e) {
  int i = blockIdx.x * blockDim.x + threadIdx.x;
  if (i < e) {
    int pos = atomicAdd(&cursor[dst[i]], 1);
    col[pos] = src[i];
  }
}

// canonical (sorted) bucket order -> deterministic float sums across graph replays
__global__ void k_sort(const int* __restrict__ row_ptr, int* __restrict__ col, int n) {
  int v = blockIdx.x * blockDim.x + threadIdx.x;
  if (v >= n) return;
  int b = row_ptr[v], e = row_ptr[v + 1];
  for (int i = b + 1; i < e; i++) {
    int key = col[i];
    int j = i - 1;
    while (j >= b && col[j] > key) { col[j + 1] = col[j]; j--; }
    col[j + 1] = key;
  }
}

// ---------------- dense layers ----------------
__global__ void k_encoder(const float* __restrict__ x, const float* __restrict__ W,
                          const float* __restrict__ bias, float* __restrict__ h, int n) {
  __shared__ float Ws[64 * 64];
  int t = threadIdx.x;
  for (int i = t; i < 64 * 64; i += 256) Ws[i] = W[i];
  __syncthreads();
  int node = blockIdx.x * 4 + (t >> 6);
  int j = t & 63;
  if (node >= n) return;
  const float* xr = x + (size_t)node * 64;
  float s = bias[j];
  #pragma unroll
  for (int i = 0; i < 64; i++) s = fmaf(xr[i], Ws[i * 64 + j], s);
  h[(size_t)node * 64 + j] = s;
}

__global__ void k_ln(const float* __restrict__ h, const float* __restrict__ g,
                     const float* __restrict__ b, float* __restrict__ hln, int n) {
  int node = blockIdx.x * 4 + (threadIdx.x >> 6);
  int lane = threadIdx.x & 63;
  if (node >= n) return;
  float v = h[(size_t)node * 64 + lane];
  float s = v;
  #pragma unroll
  for (int off = 32; off; off >>= 1) s += __shfl_xor(s, off, 64);
  float mu = s * (1.0f / 64.0f);
  float d = v - mu;
  float q = d * d;
  #pragma unroll
  for (int off = 32; off; off >>= 1) q += __shfl_xor(q, off, 64);
  float var = q * (1.0f / 64.0f);
  float rs = 1.0f / sqrtf(var + 1e-5f);
  hln[(size_t)node * 64 + lane] = d * rs * g[lane] + b[lane];
}

// agg over incoming edges, 64 features, optional {0,1} gating
template <bool WEIGHTED>
__global__ void k_agg64(const float* __restrict__ hln, const int* __restrict__ row_ptr,
                        const int* __restrict__ col, const float* __restrict__ keep_in,
                        const float* __restrict__ keep_out, float* __restrict__ agg, int n) {
  int node = blockIdx.x * 4 + (threadIdx.x >> 6);
  int lane = threadIdx.x & 63;
  if (node >= n) return;
  int b = row_ptr[node], e = row_ptr[node + 1];
  float s = 0.0f;
  for (int k = b; k < e; k++) {
    int u = col[k];
    float v = hln[(size_t)u * 64 + lane];
    if (WEIGHTED) v *= keep_out[u];
    s += v;
  }
  if (WEIGHTED) s *= keep_in[node];
  agg[(size_t)node * 64 + lane] = s;
}

// r = relu(concat(hln, agg1) @ W1 + b1) for both action nets -> [N,32] (in|out)
__global__ void k_conv1(const float* __restrict__ hln, const float* __restrict__ agg1,
                        const float* __restrict__ inW1, const float* __restrict__ inb1,
                        const float* __restrict__ outW1, const float* __restrict__ outb1,
                        float* __restrict__ r, int n) {
  __shared__ float Ws[128 * 32];  // col j<16: in_W1[:,j]; j>=16: out_W1[:,j-16]
  int t = threadIdx.x;
  for (int i = t; i < 128 * 16; i += 256) {
    int row = i >> 4, c = i & 15;
    Ws[row * 32 + c]      = inW1[i];
    Ws[row * 32 + 16 + c] = outW1[i];
  }
  __syncthreads();
  int node = blockIdx.x * 8 + (t >> 5);
  int j = t & 31;
  if (node >= n) return;
  float s = (j < 16) ? inb1[j] : outb1[j - 16];
  const float* hr = hln + (size_t)node * 64;
  const float* ar = agg1 + (size_t)node * 64;
  #pragma unroll
  for (int i = 0; i < 64; i++) s = fmaf(hr[i], Ws[i * 32 + j], s);
  #pragma unroll
  for (int i = 0; i < 64; i++) s = fmaf(ar[i], Ws[(64 + i) * 32 + j], s);
  r[(size_t)node * 32 + j] = fmaxf(s, 0.0f);
}

__global__ void k_agg32(const float* __restrict__ r, const int* __restrict__ row_ptr,
                        const int* __restrict__ col, float* __restrict__ agg2, int n) {
  int node = blockIdx.x * 8 + (threadIdx.x >> 5);
  int lane = threadIdx.x & 31;
  if (node >= n) return;
  int b = row_ptr[node], e = row_ptr[node + 1];
  float s = 0.0f;
  for (int k = b; k < e; k++) s += r[(size_t)col[k] * 32 + lane];
  agg2[(size_t)node * 32 + lane] = s;
}

// logits (conv2 of both nets) + gumbel hard decision
__global__ void k_logits(const float* __restrict__ r, const float* __restrict__ agg2,
                         const float* __restrict__ inW2, const float* __restrict__ inb2,
                         const float* __restrict__ outW2, const float* __restrict__ outb2,
                         float* __restrict__ keep_in, float* __restrict__ keep_out, int n,
                         unsigned ki0, unsigned ki1, unsigned ko0, unsigned ko1) {
  int node = blockIdx.x * blockDim.x + threadIdx.x;
  if (node >= n) return;
  const float* rr = r + (size_t)node * 32;
  const float* aa = agg2 + (size_t)node * 32;
  float il0 = inb2[0], il1 = inb2[1], ol0 = outb2[0], ol1 = outb2[1];
  #pragma unroll
  for (int i = 0; i < 16; i++) {
    float vi = rr[i], vo = rr[16 + i];
    il0 = fmaf(vi, inW2[i * 2 + 0], il0);
    il1 = fmaf(vi, inW2[i * 2 + 1], il1);
    ol0 = fmaf(vo, outW2[i * 2 + 0], ol0);
    ol1 = fmaf(vo, outW2[i * 2 + 1], ol1);
  }
  #pragma unroll
  for (int i = 0; i < 16; i++) {
    float vi = aa[i], vo = aa[16 + i];
    il0 = fmaf(vi, inW2[(16 + i) * 2 + 0], il0);
    il1 = fmaf(vi, inW2[(16 + i) * 2 + 1], il1);
    ol0 = fmaf(vo, outW2[(16 + i) * 2 + 0], ol0);
    ol1 = fmaf(vo, outW2[(16 + i) * 2 + 1], ol1);
  }
  keep_in[node]  = keep01(il0, il1, ki0, ki1, node);
  keep_out[node] = keep01(ol0, ol1, ko0, ko1, node);
}

__global__ void k_ew(const int* __restrict__ src, const int* __restrict__ dst,
                     const float* __restrict__ keep_in, const float* __restrict__ keep_out,
                     float* __restrict__ ews, int e) {
  int i = blockIdx.x * blockDim.x + threadIdx.x;
  if (i < e) ews[i] = keep_in[dst[i]] * keep_out[src[i]];
}

// h_new = concat(hln, agg) @ env_W + env_b
__global__ void k_env(const float* __restrict__ hln, const float* __restrict__ agg,
                      const float* __restrict__ W, const float* __restrict__ bias,
                      float* __restrict__ hout, int n) {
  __shared__ float Ws[128 * 64];  // 32 KiB
  int t = threadIdx.x;
  for (int i = t; i < 128 * 64; i += 256) Ws[i] = W[i];
  __syncthreads();
  int node = blockIdx.x * 4 + (t >> 6);
  int j = t & 63;
  if (node >= n) return;
  const float* hr = hln + (size_t)node * 64;
  const float* ar = agg + (size_t)node * 64;
  float s = bias[j];
  #pragma unroll
  for (int i = 0; i < 64; i++) s = fmaf(hr[i], Ws[i * 64 + j], s);
  #pragma unroll
  for (int i = 0; i < 64; i++) s = fmaf(ar[i], Ws[(64 + i) * 64 + j], s);
  hout[(size_t)node * 64 + j] = s;
}

__global__ void k_dec(const float* __restrict__ h, const float* __restrict__ W,
                      const float* __restrict__ bias, float* __restrict__ out, int n) {
  __shared__ float Ws[64 * 32];
  int t = threadIdx.x;
  for (int i = t; i < 64 * 32; i += 256) Ws[i] = W[i];
  __syncthreads();
  int node = blockIdx.x * 8 + (t >> 5);
  int j = t & 31;
  if (node >= n) return;
  const float* hr = h + (size_t)node * 64;
  float s = bias[j];
  #pragma unroll
  for (int i = 0; i < 64; i++) s = fmaf(hr[i], Ws[i * 32 + j], s);
  out[(size_t)node * 32 + j] = s;
}

// ---------------- launcher ----------------
extern "C" void kernel_launch(void* const* d_in, const int* in_sizes, int n_in,
                              void* d_out, int out_size, void* d_ws, size_t ws_size,
                              hipStream_t stream) {
  const float* x      = (const float*)d_in[0];
  const int*   ei     = (const int*)  d_in[1];
  const float* W_enc  = (const float*)d_in[2];
  const float* b_enc  = (const float*)d_in[3];
  const float* env_W  = (const float*)d_in[4];  // [3,128,64]
  const float* env_b  = (const float*)d_in[5];  // [3,64]
  const float* W_dec  = (const float*)d_in[6];
  const float* b_dec  = (const float*)d_in[7];
  const float* ln_g   = (const float*)d_in[8];
  const float* ln_b   = (const float*)d_in[9];
  const float* in_W1  = (const float*)d_in[10];
  const float* in_b1  = (const float*)d_in[11];
  const float* in_W2  = (const float*)d_in[12];
  const float* in_b2  = (const float*)d_in[13];
  const float* out_W1 = (const float*)d_in[14];
  const float* out_b1 = (const float*)d_in[15];
  const float* out_W2 = (const float*)d_in[16];
  const float* out_b2 = (const float*)d_in[17];

  const int n = NN, e = EE;
  const int* src = ei;
  const int* dst = ei + e;

  float* out_h  = (float*)d_out;            // [N,32]
  float* out_ew = out_h + (size_t)n * 32;   // [3,E]

  size_t off = 0;
  auto alloc = [&](size_t bytes) -> void* {
    void* p = (char*)d_ws + off;
    off += (bytes + 255) & ~(size_t)255;
    return p;
  };
  float* hbuf    = (float*)alloc((size_t)n * 64 * 4);
  float* hln     = (float*)alloc((size_t)n * 64 * 4);
  float* agg     = (float*)alloc((size_t)n * 64 * 4);
  float* r       = (float*)alloc((size_t)n * 32 * 4);
  float* agg2    = (float*)alloc((size_t)n * 32 * 4);
  float* keep_i  = (float*)alloc((size_t)n * 4);
  float* keep_o  = (float*)alloc((size_t)n * 4);
  int*   deg     = (int*)alloc((size_t)n * 4);
  int*   row_ptr = (int*)alloc((size_t)(n + 1) * 4);
  int*   cursor  = (int*)alloc((size_t)n * 4);
  int*   col     = (int*)alloc((size_t)e * 4);
  if (off > ws_size) return;  // ws too small: bail (test will fail loudly)

  // CSR build (same every call; graph-captured)
  hipMemsetAsync(deg, 0, (size_t)n * 4, stream);
  k_count<<<(e + 255) / 256, 256, 0, stream>>>(dst, deg, e);
  k_scan<<<1, 1024, 0, stream>>>(deg, row_ptr, cursor, n);
  k_fill<<<(e + 255) / 256, 256, 0, stream>>>(src, dst, cursor, col, e);
  k_sort<<<(n + 255) / 256, 256, 0, stream>>>(row_ptr, col, n);

  const int g4 = (n + 3) / 4;   // 4 nodes/block (64 lanes each)
  const int g8 = (n + 7) / 8;   // 8 nodes/block (32 lanes each)

  k_encoder<<<g4, 256, 0, stream>>>(x, W_enc, b_enc, hbuf, n);

  for (int l = 0; l < 3; l++) {
    TF2 kin  = tf2x32(0u, 1234u, 0u, (unsigned)(2 * l));      // fold_in(key(1234), 2l)
    TF2 kout = tf2x32(0u, 1234u, 0u, (unsigned)(2 * l + 1));  // fold_in(key(1234), 2l+1)

    k_ln<<<g4, 256, 0, stream>>>(hbuf, ln_g, ln_b, hln, n);
    k_agg64<false><<<g4, 256, 0, stream>>>(hln, row_ptr, col, nullptr, nullptr, agg, n);
    k_conv1<<<g8, 256, 0, stream>>>(hln, agg, in_W1, in_b1, out_W1, out_b1, r, n);
    k_agg32<<<g8, 256, 0, stream>>>(r, row_ptr, col, agg2, n);
    k_logits<<<(n + 255) / 256, 256, 0, stream>>>(r, agg2, in_W2, in_b2, out_W2, out_b2,
                                                  keep_i, keep_o, n,
                                                  kin.a, kin.b, kout.a, kout.b);
    k_ew<<<(e + 255) / 256, 256, 0, stream>>>(src, dst, keep_i, keep_o,
                                              out_ew + (size_t)l * e, e);
    k_agg64<true><<<g4, 256, 0, stream>>>(hln, row_ptr, col, keep_i, keep_o, agg, n);
    // hbuf is dead after k_ln -> env conv writes back into it
    k_env<<<g4, 256, 0, stream>>>(hln, agg, env_W + (size_t)l * 128 * 64,
                                  env_b + (size_t)l * 64, hbuf, n);
  }

  k_dec<<<g8, 256, 0, stream>>>(hbuf, W_dec, b_dec, out_h, n);
}

// Round 3
// 987.185 us; speedup vs baseline: 1.3581x; 1.3581x over previous
//
#include <hip/hip_runtime.h>
#include <math.h>

static constexpr int NN = 50000;   // nodes
static constexpr int EE = 800000;  // edges  (< 2^20, fits eid pack)

typedef unsigned long long ull;

// ---------------- threefry2x32 (exact JAX semantics) ----------------
struct TF2 { unsigned a, b; };

__host__ __device__ __forceinline__ TF2 tf2x32(unsigned k0, unsigned k1,
                                               unsigned x0, unsigned x1) {
  unsigned k2 = k0 ^ k1 ^ 0x1BD11BDAu;
  x0 += k0; x1 += k1;
#define TFR(r) { x0 += x1; x1 = (x1 << (r)) | (x1 >> (32 - (r))); x1 ^= x0; }
  TFR(13) TFR(15) TFR(26) TFR(6)
  x0 += k1; x1 += k2 + 1u;
  TFR(17) TFR(29) TFR(16) TFR(24)
  x0 += k2; x1 += k0 + 2u;
  TFR(13) TFR(15) TFR(26) TFR(6)
  x0 += k0; x1 += k1 + 3u;
  TFR(17) TFR(29) TFR(16) TFR(24)
  x0 += k1; x1 += k2 + 4u;
  TFR(13) TFR(15) TFR(26) TFR(6)
  x0 += k2; x1 += k0 + 5u;
#undef TFR
  TF2 r; r.a = x0; r.b = x1; return r;
}

__device__ __forceinline__ float u01_bits(unsigned w) {
  float fl = __uint_as_float((w >> 9) | 0x3f800000u) - 1.0f;
  return fmaxf(1e-20f, fl + 1e-20f);
}

// bits[f] = TF(key,(0,f)).a ^ .b   (jax threefry_partitionable)
__device__ __forceinline__ float keep01(float l0, float l1, unsigned k0, unsigned k1, int node) {
  unsigned f0 = 2u * (unsigned)node, f1 = f0 + 1u;
  TF2 t0 = tf2x32(k0, k1, 0u, f0);
  TF2 t1 = tf2x32(k0, k1, 0u, f1);
  float g0 = -logf(-logf(u01_bits(t0.a ^ t0.b)));
  float g1 = -logf(-logf(u01_bits(t1.a ^ t1.b)));
  float z0 = l0 + g0, z1 = l1 + g1;   // tau == 1
  float m  = fmaxf(z0, z1);
  float e0 = expf(z0 - m), e1 = expf(z1 - m);
  float s  = e0 + e1;
  float y0 = e0 / s, y1 = e1 / s;
  return (y1 > y0) ? 0.0f : 1.0f;     // ties -> class 0, like jnp.argmax
}

// ---------------- CSR build (dst-indexed, canonical) ----------------
__global__ void k_count(const int* __restrict__ dst, int* __restrict__ deg, int e) {
  int i = blockIdx.x * blockDim.x + threadIdx.x;
  if (i < e) atomicAdd(&deg[dst[i]], 1);
}

// 3-phase exclusive scan of deg[0..n) -> row_ptr/cursor ; row_ptr[n]=E
__global__ void k_bsum(const int* __restrict__ deg, int* __restrict__ bsum, int n) {
  int i = blockIdx.x * 256 + threadIdx.x;
  int v = (i < n) ? deg[i] : 0;
  #pragma unroll
  for (int off = 32; off; off >>= 1) v += __shfl_xor(v, off, 64);
  __shared__ int ws[4];
  if ((threadIdx.x & 63) == 0) ws[threadIdx.x >> 6] = v;
  __syncthreads();
  if (threadIdx.x == 0) bsum[blockIdx.x] = ws[0] + ws[1] + ws[2] + ws[3];
}

__global__ void k_bscan(const int* __restrict__ bsum, int* __restrict__ bpref,
                        int nb, int* __restrict__ row_ptr, int n) {
  __shared__ int s[256];
  int t = threadIdx.x;
  int v = (t < nb) ? bsum[t] : 0;
  s[t] = v; __syncthreads();
  for (int off = 1; off < 256; off <<= 1) {
    int u = (t >= off) ? s[t - off] : 0;
    __syncthreads();
    s[t] += u;
    __syncthreads();
  }
  bpref[t] = s[t] - v;                 // exclusive
  if (t == 0) row_ptr[n] = s[255];     // total = E
}

__global__ void k_prefix(const int* __restrict__ deg, const int* __restrict__ bpref,
                         int* __restrict__ row_ptr, int* __restrict__ cursor, int n) {
  __shared__ int s[256];
  int t = threadIdx.x;
  int i = blockIdx.x * 256 + t;
  int v = (i < n) ? deg[i] : 0;
  s[t] = v; __syncthreads();
  for (int off = 1; off < 256; off <<= 1) {
    int u = (t >= off) ? s[t - off] : 0;
    __syncthreads();
    s[t] += u;
    __syncthreads();
  }
  if (i < n) {
    int ex = s[t] - v + bpref[blockIdx.x];
    row_ptr[i] = ex; cursor[i] = ex;
  }
}

// pack (src, edge_id): key = src<<20 | eid  -> sort canonical incl. duplicates
__global__ void k_fill(const int* __restrict__ src, const int* __restrict__ dst,
                       int* __restrict__ cursor, ull* __restrict__ ce, int e) {
  int i = blockIdx.x * blockDim.x + threadIdx.x;
  if (i < e) {
    int pos = atomicAdd(&cursor[dst[i]], 1);
    ce[pos] = ((ull)(unsigned)src[i] << 20) | (unsigned)i;
  }
}

__global__ void k_sort(const int* __restrict__ row_ptr, ull* __restrict__ ce, int n) {
  int v = blockIdx.x * blockDim.x + threadIdx.x;
  if (v >= n) return;
  int b = row_ptr[v], e = row_ptr[v + 1];
  for (int i = b + 1; i < e; i++) {
    ull key = ce[i];
    int j = i - 1;
    while (j >= b && ce[j] > key) { ce[j + 1] = ce[j]; j--; }
    ce[j + 1] = key;
  }
}

// ---------------- dense layers ----------------
// encoder + fused LayerNorm (64 feats of a node live in one 64-lane wave)
__global__ void k_enc_ln(const float* __restrict__ x, const float* __restrict__ W,
                         const float* __restrict__ bias, const float* __restrict__ g,
                         const float* __restrict__ bb, float* __restrict__ hln, int n) {
  __shared__ float Ws[64 * 64];
  for (int i = threadIdx.x; i < 64 * 64; i += 256) Ws[i] = W[i];
  __syncthreads();
  int node = blockIdx.x * 4 + (threadIdx.x >> 6);
  int j = threadIdx.x & 63;
  if (node >= n) return;
  const float* xr = x + (size_t)node * 64;
  float s = bias[j];
  #pragma unroll
  for (int i = 0; i < 64; i++) s = fmaf(xr[i], Ws[i * 64 + j], s);
  float t = s;
  #pragma unroll
  for (int off = 32; off; off >>= 1) t += __shfl_xor(t, off, 64);
  float mu = t * (1.0f / 64.0f);
  float d = s - mu;
  float q = d * d;
  #pragma unroll
  for (int off = 32; off; off >>= 1) q += __shfl_xor(q, off, 64);
  float rs = 1.0f / sqrtf(q * (1.0f / 64.0f) + 1e-5f);
  hln[(size_t)node * 64 + j] = d * rs * g[j] + bb[j];
}

// agg over incoming edges, 64 feats; WEIGHTED also emits ew[eid]=ki*ko
template <bool WEIGHTED>
__global__ void k_agg64(const float* __restrict__ hln, const int* __restrict__ row_ptr,
                        const ull* __restrict__ ce, const float* __restrict__ keep_in,
                        const float* __restrict__ keep_out, float* __restrict__ ew,
                        float* __restrict__ agg, int n) {
  int node = blockIdx.x * 4 + (threadIdx.x >> 6);
  int lane = threadIdx.x & 63;
  if (node >= n) return;
  int b = row_ptr[node], e = row_ptr[node + 1];
  float ki = WEIGHTED ? keep_in[node] : 0.0f;
  float s0 = 0.f, s1 = 0.f, s2 = 0.f, s3 = 0.f;
  int k = b;
  for (; k + 4 <= e; k += 4) {
    ull c0 = ce[k], c1 = ce[k + 1], c2 = ce[k + 2], c3 = ce[k + 3];
    int u0 = (int)(c0 >> 20), u1 = (int)(c1 >> 20),
        u2 = (int)(c2 >> 20), u3 = (int)(c3 >> 20);
    float v0 = hln[(size_t)u0 * 64 + lane], v1 = hln[(size_t)u1 * 64 + lane],
          v2 = hln[(size_t)u2 * 64 + lane], v3 = hln[(size_t)u3 * 64 + lane];
    if (WEIGHTED) {
      float ko0 = keep_out[u0], ko1 = keep_out[u1],
            ko2 = keep_out[u2], ko3 = keep_out[u3];
      v0 *= ko0; v1 *= ko1; v2 *= ko2; v3 *= ko3;
      if (lane == 0) {
        ew[(unsigned)(c0 & 0xFFFFFu)] = ki * ko0;
        ew[(unsigned)(c1 & 0xFFFFFu)] = ki * ko1;
        ew[(unsigned)(c2 & 0xFFFFFu)] = ki * ko2;
        ew[(unsigned)(c3 & 0xFFFFFu)] = ki * ko3;
      }
    }
    s0 += v0; s1 += v1; s2 += v2; s3 += v3;
  }
  for (; k < e; k++) {
    ull c = ce[k];
    int u = (int)(c >> 20);
    float v = hln[(size_t)u * 64 + lane];
    if (WEIGHTED) {
      float ko = keep_out[u];
      v *= ko;
      if (lane == 0) ew[(unsigned)(c & 0xFFFFFu)] = ki * ko;
    }
    s0 += v;
  }
  float s = (s0 + s1) + (s2 + s3);
  if (WEIGHTED) s *= ki;
  agg[(size_t)node * 64 + lane] = s;
}

// r = relu(concat(hln, agg1) @ W1 + b1) for both action nets -> [N,32] (in|out)
__global__ void k_conv1(const float* __restrict__ hln, const float* __restrict__ agg1,
                        const float* __restrict__ inW1, const float* __restrict__ inb1,
                        const float* __restrict__ outW1, const float* __restrict__ outb1,
                        float* __restrict__ r, int n) {
  __shared__ float Ws[128 * 32];  // col j<16: in_W1[:,j]; j>=16: out_W1[:,j-16]
  int t = threadIdx.x;
  for (int i = t; i < 128 * 16; i += 256) {
    int row = i >> 4, c = i & 15;
    Ws[row * 32 + c]      = inW1[i];
    Ws[row * 32 + 16 + c] = outW1[i];
  }
  __syncthreads();
  int node = blockIdx.x * 8 + (t >> 5);
  int j = t & 31;
  if (node >= n) return;
  float s = (j < 16) ? inb1[j] : outb1[j - 16];
  const float* hr = hln + (size_t)node * 64;
  const float* ar = agg1 + (size_t)node * 64;
  #pragma unroll
  for (int i = 0; i < 64; i++) s = fmaf(hr[i], Ws[i * 32 + j], s);
  #pragma unroll
  for (int i = 0; i < 64; i++) s = fmaf(ar[i], Ws[(64 + i) * 32 + j], s);
  r[(size_t)node * 32 + j] = fmaxf(s, 0.0f);
}

// fused: agg32 gather + conv2 dot (16-lane reduce) + gumbel decisions
__global__ void k_agg32_logits(const float* __restrict__ r, const int* __restrict__ row_ptr,
                               const ull* __restrict__ ce,
                               const float* __restrict__ inW2, const float* __restrict__ inb2,
                               const float* __restrict__ outW2, const float* __restrict__ outb2,
                               float* __restrict__ keep_in, float* __restrict__ keep_out, int n,
                               unsigned ki0, unsigned ki1, unsigned ko0, unsigned ko1) {
  int node = blockIdx.x * 8 + (threadIdx.x >> 5);
  int j = threadIdx.x & 31;
  if (node >= n) return;
  int b = row_ptr[node], e = row_ptr[node + 1];
  float s0 = 0.f, s1 = 0.f;
  int k = b;
  for (; k + 2 <= e; k += 2) {
    int u0 = (int)(ce[k] >> 20), u1 = (int)(ce[k + 1] >> 20);
    s0 += r[(size_t)u0 * 32 + j];
    s1 += r[(size_t)u1 * 32 + j];
  }
  if (k < e) s0 += r[(size_t)(ce[k] >> 20) * 32 + j];
  float agg = s0 + s1;
  float self = r[(size_t)node * 32 + j];
  float p0, p1;
  if (j < 16) {
    p0 = self * inW2[j * 2 + 0] + agg * inW2[(16 + j) * 2 + 0];
    p1 = self * inW2[j * 2 + 1] + agg * inW2[(16 + j) * 2 + 1];
  } else {
    int j2 = j - 16;
    p0 = self * outW2[j2 * 2 + 0] + agg * outW2[(16 + j2) * 2 + 0];
    p1 = self * outW2[j2 * 2 + 1] + agg * outW2[(16 + j2) * 2 + 1];
  }
  #pragma unroll
  for (int off = 8; off; off >>= 1) {  // reduce within each 16-lane group
    p0 += __shfl_xor(p0, off, 64);
    p1 += __shfl_xor(p1, off, 64);
  }
  if (j == 0)  keep_in[node]  = keep01(p0 + inb2[0],  p1 + inb2[1],  ki0, ki1, node);
  if (j == 16) keep_out[node] = keep01(p0 + outb2[0], p1 + outb2[1], ko0, ko1, node);
}

// h_new = concat(hln, agg) @ env_W + env_b ; LN-fused variant for next layer
template <bool LN>
__global__ void k_env(const float* __restrict__ hln, const float* __restrict__ agg,
                      const float* __restrict__ W, const float* __restrict__ bias,
                      const float* __restrict__ g, const float* __restrict__ bb,
                      float* __restrict__ hout, int n) {
  __shared__ float Ws[128 * 64];  // 32 KiB
  int t = threadIdx.x;
  for (int i = t; i < 128 * 64; i += 256) Ws[i] = W[i];
  __syncthreads();
  int node = blockIdx.x * 4 + (t >> 6);
  int j = t & 63;
  if (node >= n) return;
  const float* hr = hln + (size_t)node * 64;
  const float* ar = agg + (size_t)node * 64;
  float s = bias[j];
  #pragma unroll
  for (int i = 0; i < 64; i++) s = fmaf(hr[i], Ws[i * 64 + j], s);
  #pragma unroll
  for (int i = 0; i < 64; i++) s = fmaf(ar[i], Ws[(64 + i) * 64 + j], s);
  if (LN) {
    float tt = s;
    #pragma unroll
    for (int off = 32; off; off >>= 1) tt += __shfl_xor(tt, off, 64);
    float mu = tt * (1.0f / 64.0f);
    float d = s - mu;
    float q = d * d;
    #pragma unroll
    for (int off = 32; off; off >>= 1) q += __shfl_xor(q, off, 64);
    float rs = 1.0f / sqrtf(q * (1.0f / 64.0f) + 1e-5f);
    hout[(size_t)node * 64 + j] = d * rs * g[j] + bb[j];
  } else {
    hout[(size_t)node * 64 + j] = s;
  }
}

__global__ void k_dec(const float* __restrict__ h, const float* __restrict__ W,
                      const float* __restrict__ bias, float* __restrict__ out, int n) {
  __shared__ float Ws[64 * 32];
  int t = threadIdx.x;
  for (int i = t; i < 64 * 32; i += 256) Ws[i] = W[i];
  __syncthreads();
  int node = blockIdx.x * 8 + (t >> 5);
  int j = t & 31;
  if (node >= n) return;
  const float* hr = h + (size_t)node * 64;
  float s = bias[j];
  #pragma unroll
  for (int i = 0; i < 64; i++) s = fmaf(hr[i], Ws[i * 32 + j], s);
  out[(size_t)node * 32 + j] = s;
}

// ---------------- launcher ----------------
extern "C" void kernel_launch(void* const* d_in, const int* in_sizes, int n_in,
                              void* d_out, int out_size, void* d_ws, size_t ws_size,
                              hipStream_t stream) {
  const float* x      = (const float*)d_in[0];
  const int*   ei     = (const int*)  d_in[1];
  const float* W_enc  = (const float*)d_in[2];
  const float* b_enc  = (const float*)d_in[3];
  const float* env_W  = (const float*)d_in[4];  // [3,128,64]
  const float* env_b  = (const float*)d_in[5];  // [3,64]
  const float* W_dec  = (const float*)d_in[6];
  const float* b_dec  = (const float*)d_in[7];
  const float* ln_g   = (const float*)d_in[8];
  const float* ln_b   = (const float*)d_in[9];
  const float* in_W1  = (const float*)d_in[10];
  const float* in_b1  = (const float*)d_in[11];
  const float* in_W2  = (const float*)d_in[12];
  const float* in_b2  = (const float*)d_in[13];
  const float* out_W1 = (const float*)d_in[14];
  const float* out_b1 = (const float*)d_in[15];
  const float* out_W2 = (const float*)d_in[16];
  const float* out_b2 = (const float*)d_in[17];

  const int n = NN, e = EE;
  const int* src = ei;
  const int* dst = ei + e;

  float* out_h  = (float*)d_out;            // [N,32]
  float* out_ew = out_h + (size_t)n * 32;   // [3,E]

  size_t off = 0;
  auto alloc = [&](size_t bytes) -> void* {
    void* p = (char*)d_ws + off;
    off += (bytes + 255) & ~(size_t)255;
    return p;
  };
  float* hlnA    = (float*)alloc((size_t)n * 64 * 4);
  float* hlnB    = (float*)alloc((size_t)n * 64 * 4);
  float* agg     = (float*)alloc((size_t)n * 64 * 4);
  float* r       = (float*)alloc((size_t)n * 32 * 4);
  float* keep_i  = (float*)alloc((size_t)n * 4);
  float* keep_o  = (float*)alloc((size_t)n * 4);
  int*   deg     = (int*)alloc((size_t)n * 4);
  int*   row_ptr = (int*)alloc((size_t)(n + 1) * 4);
  int*   cursor  = (int*)alloc((size_t)n * 4);
  int*   bsum    = (int*)alloc(256 * 4);
  int*   bpref   = (int*)alloc(256 * 4);
  ull*   ce      = (ull*)alloc((size_t)e * 8);
  if (off > ws_size) return;  // ws too small: bail loudly

  const int nb = (n + 255) / 256;  // 196

  // CSR build (canonical: sort key includes edge id)
  hipMemsetAsync(deg, 0, (size_t)n * 4, stream);
  k_count<<<(e + 255) / 256, 256, 0, stream>>>(dst, deg, e);
  k_bsum<<<nb, 256, 0, stream>>>(deg, bsum, n);
  k_bscan<<<1, 256, 0, stream>>>(bsum, bpref, nb, row_ptr, n);
  k_prefix<<<nb, 256, 0, stream>>>(deg, bpref, row_ptr, cursor, n);
  k_fill<<<(e + 255) / 256, 256, 0, stream>>>(src, dst, cursor, ce, e);
  k_sort<<<(n + 255) / 256, 256, 0, stream>>>(row_ptr, ce, n);

  const int g4 = (n + 3) / 4;   // 4 nodes/block (64 lanes each)
  const int g8 = (n + 7) / 8;   // 8 nodes/block (32 lanes each)

  k_enc_ln<<<g4, 256, 0, stream>>>(x, W_enc, b_enc, ln_g, ln_b, hlnA, n);

  float* hln = hlnA;
  float* hln_next = hlnB;
  for (int l = 0; l < 3; l++) {
    TF2 kin  = tf2x32(0u, 1234u, 0u, (unsigned)(2 * l));      // fold_in(key(1234), 2l)
    TF2 kout = tf2x32(0u, 1234u, 0u, (unsigned)(2 * l + 1));  // fold_in(key(1234), 2l+1)

    k_agg64<false><<<g4, 256, 0, stream>>>(hln, row_ptr, ce, nullptr, nullptr, nullptr, agg, n);
    k_conv1<<<g8, 256, 0, stream>>>(hln, agg, in_W1, in_b1, out_W1, out_b1, r, n);
    k_agg32_logits<<<g8, 256, 0, stream>>>(r, row_ptr, ce, in_W2, in_b2, out_W2, out_b2,
                                           keep_i, keep_o, n,
                                           kin.a, kin.b, kout.a, kout.b);
    k_agg64<true><<<g4, 256, 0, stream>>>(hln, row_ptr, ce, keep_i, keep_o,
                                          out_ew + (size_t)l * e, agg, n);
    if (l < 2) {
      k_env<true><<<g4, 256, 0, stream>>>(hln, agg, env_W + (size_t)l * 128 * 64,
                                          env_b + (size_t)l * 64, ln_g, ln_b, hln_next, n);
    } else {
      k_env<false><<<g4, 256, 0, stream>>>(hln, agg, env_W + (size_t)l * 128 * 64,
                                           env_b + (size_t)l * 64, ln_g, ln_b, hln_next, n);
    }
    float* tmp = hln; hln = hln_next; hln_next = tmp;
  }

  // hln now points at the raw layer-2 env output
  k_dec<<<g8, 256, 0, stream>>>(hln, W_dec, b_dec, out_h, n);
}

// Round 4
// 704.419 us; speedup vs baseline: 1.9033x; 1.4014x over previous
//
#include <hip/hip_runtime.h>
#include <math.h>

static constexpr int NN = 50000;   // nodes
static constexpr int EE = 800000;  // edges (< 2^20, fits eid pack)

typedef unsigned long long ull;

// ---------------- threefry2x32 (exact JAX semantics) ----------------
struct TF2 { unsigned a, b; };

__host__ __device__ __forceinline__ TF2 tf2x32(unsigned k0, unsigned k1,
                                               unsigned x0, unsigned x1) {
  unsigned k2 = k0 ^ k1 ^ 0x1BD11BDAu;
  x0 += k0; x1 += k1;
#define TFR(r) { x0 += x1; x1 = (x1 << (r)) | (x1 >> (32 - (r))); x1 ^= x0; }
  TFR(13) TFR(15) TFR(26) TFR(6)
  x0 += k1; x1 += k2 + 1u;
  TFR(17) TFR(29) TFR(16) TFR(24)
  x0 += k2; x1 += k0 + 2u;
  TFR(13) TFR(15) TFR(26) TFR(6)
  x0 += k0; x1 += k1 + 3u;
  TFR(17) TFR(29) TFR(16) TFR(24)
  x0 += k1; x1 += k2 + 4u;
  TFR(13) TFR(15) TFR(26) TFR(6)
  x0 += k2; x1 += k0 + 5u;
#undef TFR
  TF2 r; r.a = x0; r.b = x1; return r;
}

__device__ __forceinline__ float u01_bits(unsigned w) {
  float fl = __uint_as_float((w >> 9) | 0x3f800000u) - 1.0f;
  return fmaxf(1e-20f, fl + 1e-20f);
}

// bits[f] = TF(key,(0,f)).a ^ .b   (jax threefry_partitionable)
__device__ __forceinline__ float keep01(float l0, float l1, unsigned k0, unsigned k1, int node) {
  unsigned f0 = 2u * (unsigned)node, f1 = f0 + 1u;
  TF2 t0 = tf2x32(k0, k1, 0u, f0);
  TF2 t1 = tf2x32(k0, k1, 0u, f1);
  float g0 = -logf(-logf(u01_bits(t0.a ^ t0.b)));
  float g1 = -logf(-logf(u01_bits(t1.a ^ t1.b)));
  float z0 = l0 + g0, z1 = l1 + g1;   // tau == 1
  float m  = fmaxf(z0, z1);
  float e0 = expf(z0 - m), e1 = expf(z1 - m);
  float s  = e0 + e1;
  float y0 = e0 / s, y1 = e1 / s;
  return (y1 > y0) ? 0.0f : 1.0f;     // ties -> class 0, like jnp.argmax
}

// ---------------- CSR build (dst-indexed; bucket order arbitrary) ----------------
__global__ void k_count(const int* __restrict__ dst, int* __restrict__ deg, int e) {
  int i = blockIdx.x * blockDim.x + threadIdx.x;
  if (i < e) atomicAdd(&deg[dst[i]], 1);
}

__global__ void k_bsum(const int* __restrict__ deg, int* __restrict__ bsum, int n) {
  int i = blockIdx.x * 256 + threadIdx.x;
  int v = (i < n) ? deg[i] : 0;
  #pragma unroll
  for (int off = 32; off; off >>= 1) v += __shfl_xor(v, off, 64);
  __shared__ int ws[4];
  if ((threadIdx.x & 63) == 0) ws[threadIdx.x >> 6] = v;
  __syncthreads();
  if (threadIdx.x == 0) bsum[blockIdx.x] = ws[0] + ws[1] + ws[2] + ws[3];
}

__global__ void k_bscan(const int* __restrict__ bsum, int* __restrict__ bpref,
                        int nb, int* __restrict__ row_ptr, int n) {
  __shared__ int s[256];
  int t = threadIdx.x;
  int v = (t < nb) ? bsum[t] : 0;
  s[t] = v; __syncthreads();
  for (int off = 1; off < 256; off <<= 1) {
    int u = (t >= off) ? s[t - off] : 0;
    __syncthreads();
    s[t] += u;
    __syncthreads();
  }
  bpref[t] = s[t] - v;                 // exclusive
  if (t == 0) row_ptr[n] = s[255];     // total = E
}

__global__ void k_prefix(const int* __restrict__ deg, const int* __restrict__ bpref,
                         int* __restrict__ row_ptr, int* __restrict__ cursor, int n) {
  __shared__ int s[256];
  int t = threadIdx.x;
  int i = blockIdx.x * 256 + t;
  int v = (i < n) ? deg[i] : 0;
  s[t] = v; __syncthreads();
  for (int off = 1; off < 256; off <<= 1) {
    int u = (t >= off) ? s[t - off] : 0;
    __syncthreads();
    s[t] += u;
    __syncthreads();
  }
  if (i < n) {
    int ex = s[t] - v + bpref[blockIdx.x];
    row_ptr[i] = ex; cursor[i] = ex;
  }
}

// pack (src, edge_id): key = src<<20 | eid
__global__ void k_fill(const int* __restrict__ src, const int* __restrict__ dst,
                       int* __restrict__ cursor, ull* __restrict__ ce, int e) {
  int i = blockIdx.x * blockDim.x + threadIdx.x;
  if (i < e) {
    int pos = atomicAdd(&cursor[dst[i]], 1);
    ce[pos] = ((ull)(unsigned)src[i] << 20) | (unsigned)i;
  }
}

// ---------------- dense / fused kernels ----------------
// encoder + fused LayerNorm
__global__ void k_enc_ln(const float* __restrict__ x, const float* __restrict__ W,
                         const float* __restrict__ bias, const float* __restrict__ g,
                         const float* __restrict__ bb, float* __restrict__ hln) {
  __shared__ float Ws[64 * 64];
  for (int i = threadIdx.x; i < 64 * 64; i += 256) Ws[i] = W[i];
  __syncthreads();
  int node = blockIdx.x * 4 + (threadIdx.x >> 6);
  int j = threadIdx.x & 63;
  const float* xr = x + (size_t)node * 64;
  float s = bias[j];
  #pragma unroll
  for (int i = 0; i < 64; i++) s = fmaf(xr[i], Ws[i * 64 + j], s);
  float t = s;
  #pragma unroll
  for (int off = 32; off; off >>= 1) t += __shfl_xor(t, off, 64);
  float mu = t * (1.0f / 64.0f);
  float d = s - mu;
  float q = d * d;
  #pragma unroll
  for (int off = 32; off; off >>= 1) q += __shfl_xor(q, off, 64);
  float rs = 1.0f / sqrtf(q * (1.0f / 64.0f) + 1e-5f);
  hln[(size_t)node * 64 + j] = d * rs * g[j] + bb[j];
}

// A: unweighted agg64 + conv1 (both action nets) -> r [N,32]
__global__ void k_aggA(const float* __restrict__ hln, const int* __restrict__ row_ptr,
                       const ull* __restrict__ ce,
                       const float* __restrict__ inW1, const float* __restrict__ inb1,
                       const float* __restrict__ outW1, const float* __restrict__ outb1,
                       float* __restrict__ r) {
  __shared__ float Ws[128 * 32];  // col j<16: in_W1[:,j]; j>=16: out_W1[:,j-16]
  __shared__ __align__(16) float st[4][128];
  int t = threadIdx.x;
  for (int i = t; i < 128 * 16; i += 256) {
    int row = i >> 4, c = i & 15;
    Ws[row * 32 + c]      = inW1[i];
    Ws[row * 32 + 16 + c] = outW1[i];
  }
  int w = t >> 6, lane = t & 63;
  int node = blockIdx.x * 4 + w;
  float hv = hln[(size_t)node * 64 + lane];
  int b = row_ptr[node], e = row_ptr[node + 1];
  float s0 = 0.f, s1 = 0.f, s2 = 0.f, s3 = 0.f;
  for (int base = b; base < e; base += 64) {
    int idx = base + lane;
    int u_l = (idx < e) ? (int)(ce[idx] >> 20) : 0;
    int cnt = min(64, e - base);
    int k = 0;
    for (; k + 4 <= cnt; k += 4) {
      int u0 = __shfl(u_l, k, 64),     u1 = __shfl(u_l, k + 1, 64),
          u2 = __shfl(u_l, k + 2, 64), u3 = __shfl(u_l, k + 3, 64);
      s0 += hln[(size_t)u0 * 64 + lane];
      s1 += hln[(size_t)u1 * 64 + lane];
      s2 += hln[(size_t)u2 * 64 + lane];
      s3 += hln[(size_t)u3 * 64 + lane];
    }
    for (; k < cnt; k++)
      s0 += hln[(size_t)__shfl(u_l, k, 64) * 64 + lane];
  }
  st[w][lane]      = hv;
  st[w][64 + lane] = (s0 + s1) + (s2 + s3);
  __syncthreads();   // N%4==0 -> all 256 threads reach (also fences Ws)
  int jo = lane & 31, half = lane >> 5;
  const float* sv = &st[w][half * 64];
  float acc = 0.f;
  #pragma unroll
  for (int i = 0; i < 64; i += 4) {
    float4 c4 = *(const float4*)(sv + i);
    acc = fmaf(c4.x, Ws[(half * 64 + i    ) * 32 + jo], acc);
    acc = fmaf(c4.y, Ws[(half * 64 + i + 1) * 32 + jo], acc);
    acc = fmaf(c4.z, Ws[(half * 64 + i + 2) * 32 + jo], acc);
    acc = fmaf(c4.w, Ws[(half * 64 + i + 3) * 32 + jo], acc);
  }
  acc += __shfl_xor(acc, 32, 64);
  if (half == 0) {
    float bias = (jo < 16) ? inb1[jo] : outb1[jo - 16];
    r[(size_t)node * 32 + jo] = fmaxf(acc + bias, 0.f);
  }
}

// B: agg32 gather + conv2 dot + gumbel decisions
__global__ void k_aggB(const float* __restrict__ r, const int* __restrict__ row_ptr,
                       const ull* __restrict__ ce,
                       const float* __restrict__ inW2, const float* __restrict__ inb2,
                       const float* __restrict__ outW2, const float* __restrict__ outb2,
                       float* __restrict__ keep_in, float* __restrict__ keep_out,
                       unsigned ki0, unsigned ki1, unsigned ko0, unsigned ko1) {
  int t = threadIdx.x;
  int node = blockIdx.x * 8 + (t >> 5);
  int j = t & 31;
  int b = row_ptr[node], e = row_ptr[node + 1];
  float s0 = 0.f, s1 = 0.f;
  for (int base = b; base < e; base += 32) {
    int idx = base + j;
    int u_l = (idx < e) ? (int)(ce[idx] >> 20) : 0;
    int cnt = min(32, e - base);
    int k = 0;
    for (; k + 2 <= cnt; k += 2) {
      int u0 = __shfl(u_l, k, 32), u1 = __shfl(u_l, k + 1, 32);
      s0 += r[(size_t)u0 * 32 + j];
      s1 += r[(size_t)u1 * 32 + j];
    }
    if (k < cnt) s0 += r[(size_t)__shfl(u_l, k, 32) * 32 + j];
  }
  float agg = s0 + s1;
  float self = r[(size_t)node * 32 + j];
  float p0, p1;
  if (j < 16) {
    p0 = self * inW2[j * 2 + 0] + agg * inW2[(16 + j) * 2 + 0];
    p1 = self * inW2[j * 2 + 1] + agg * inW2[(16 + j) * 2 + 1];
  } else {
    int j2 = j - 16;
    p0 = self * outW2[j2 * 2 + 0] + agg * outW2[(16 + j2) * 2 + 0];
    p1 = self * outW2[j2 * 2 + 1] + agg * outW2[(16 + j2) * 2 + 1];
  }
  #pragma unroll
  for (int off = 8; off; off >>= 1) {
    p0 += __shfl_xor(p0, off, 64);
    p1 += __shfl_xor(p1, off, 64);
  }
  if (j == 0)  keep_in[node]  = keep01(p0 + inb2[0],  p1 + inb2[1],  ki0, ki1, node);
  if (j == 16) keep_out[node] = keep01(p0 + outb2[0], p1 + outb2[1], ko0, ko1, node);
}

// C: weighted agg64 (+ew write) + env conv (+optional LN). W read from global (L2-hot).
template <bool LN>
__global__ void k_aggC(const float* __restrict__ hln, const int* __restrict__ row_ptr,
                       const ull* __restrict__ ce, const float* __restrict__ keep_in,
                       const float* __restrict__ keep_out, float* __restrict__ ew,
                       const float* __restrict__ W, const float* __restrict__ bias,
                       const float* __restrict__ g, const float* __restrict__ bb,
                       float* __restrict__ hout) {
  __shared__ __align__(16) float st[4][128];
  int t = threadIdx.x;
  int w = t >> 6, lane = t & 63;
  int node = blockIdx.x * 4 + w;
  float ki = keep_in[node];
  float hv = hln[(size_t)node * 64 + lane];
  int b = row_ptr[node], e = row_ptr[node + 1];
  float s0 = 0.f, s1 = 0.f, s2 = 0.f, s3 = 0.f;
  for (int base = b; base < e; base += 64) {
    int idx = base + lane;
    int u_l = 0; float ko_l = 0.f;
    if (idx < e) {
      ull c = ce[idx];
      u_l = (int)(c >> 20);
      ko_l = keep_out[u_l];
      ew[(unsigned)(c & 0xFFFFFu)] = ki * ko_l;   // exact {0,1} product
    }
    if (ki != 0.f) {                              // wave-uniform skip
      int cnt = min(64, e - base);
      int k = 0;
      for (; k + 4 <= cnt; k += 4) {
        int u0 = __shfl(u_l, k, 64),     u1 = __shfl(u_l, k + 1, 64),
            u2 = __shfl(u_l, k + 2, 64), u3 = __shfl(u_l, k + 3, 64);
        float w0 = __shfl(ko_l, k, 64),     w1 = __shfl(ko_l, k + 1, 64),
              w2 = __shfl(ko_l, k + 2, 64), w3 = __shfl(ko_l, k + 3, 64);
        if (w0 != 0.f) s0 += hln[(size_t)u0 * 64 + lane];  // uniform branches
        if (w1 != 0.f) s1 += hln[(size_t)u1 * 64 + lane];
        if (w2 != 0.f) s2 += hln[(size_t)u2 * 64 + lane];
        if (w3 != 0.f) s3 += hln[(size_t)u3 * 64 + lane];
      }
      for (; k < cnt; k++) {
        int u0 = __shfl(u_l, k, 64);
        float w0 = __shfl(ko_l, k, 64);
        if (w0 != 0.f) s0 += hln[(size_t)u0 * 64 + lane];
      }
    }
  }
  float s = ((s0 + s1) + (s2 + s3)) * ki;
  st[w][lane]      = hv;
  st[w][64 + lane] = s;
  // no __syncthreads: st[w] is wave-private (same-wave RAW handled by lgkmcnt)
  float a0 = bias[lane], a1 = 0.f, a2 = 0.f, a3 = 0.f;
  #pragma unroll 4
  for (int i = 0; i < 128; i += 4) {
    float4 c4 = *(const float4*)(&st[w][i]);
    a0 = fmaf(c4.x, W[(i    ) * 64 + lane], a0);
    a1 = fmaf(c4.y, W[(i + 1) * 64 + lane], a1);
    a2 = fmaf(c4.z, W[(i + 2) * 64 + lane], a2);
    a3 = fmaf(c4.w, W[(i + 3) * 64 + lane], a3);
  }
  float acc = (a0 + a1) + (a2 + a3);
  if (LN) {
    float tt = acc;
    #pragma unroll
    for (int off = 32; off; off >>= 1) tt += __shfl_xor(tt, off, 64);
    float mu = tt * (1.0f / 64.0f);
    float d = acc - mu;
    float q = d * d;
    #pragma unroll
    for (int off = 32; off; off >>= 1) q += __shfl_xor(q, off, 64);
    float rs = 1.0f / sqrtf(q * (1.0f / 64.0f) + 1e-5f);
    hout[(size_t)node * 64 + lane] = d * rs * g[lane] + bb[lane];
  } else {
    hout[(size_t)node * 64 + lane] = acc;
  }
}

__global__ void k_dec(const float* __restrict__ h, const float* __restrict__ W,
                      const float* __restrict__ bias, float* __restrict__ out) {
  __shared__ float Ws[64 * 32];
  int t = threadIdx.x;
  for (int i = t; i < 64 * 32; i += 256) Ws[i] = W[i];
  __syncthreads();
  int node = blockIdx.x * 8 + (t >> 5);
  int j = t & 31;
  const float* hr = h + (size_t)node * 64;
  float s = bias[j];
  #pragma unroll
  for (int i = 0; i < 64; i++) s = fmaf(hr[i], Ws[i * 32 + j], s);
  out[(size_t)node * 32 + j] = s;
}

// ---------------- launcher ----------------
extern "C" void kernel_launch(void* const* d_in, const int* in_sizes, int n_in,
                              void* d_out, int out_size, void* d_ws, size_t ws_size,
                              hipStream_t stream) {
  const float* x      = (const float*)d_in[0];
  const int*   ei     = (const int*)  d_in[1];
  const float* W_enc  = (const float*)d_in[2];
  const float* b_enc  = (const float*)d_in[3];
  const float* env_W  = (const float*)d_in[4];  // [3,128,64]
  const float* env_b  = (const float*)d_in[5];  // [3,64]
  const float* W_dec  = (const float*)d_in[6];
  const float* b_dec  = (const float*)d_in[7];
  const float* ln_g   = (const float*)d_in[8];
  const float* ln_b   = (const float*)d_in[9];
  const float* in_W1  = (const float*)d_in[10];
  const float* in_b1  = (const float*)d_in[11];
  const float* in_W2  = (const float*)d_in[12];
  const float* in_b2  = (const float*)d_in[13];
  const float* out_W1 = (const float*)d_in[14];
  const float* out_b1 = (const float*)d_in[15];
  const float* out_W2 = (const float*)d_in[16];
  const float* out_b2 = (const float*)d_in[17];

  const int n = NN, e = EE;
  const int* src = ei;
  const int* dst = ei + e;

  float* out_h  = (float*)d_out;            // [N,32]
  float* out_ew = out_h + (size_t)n * 32;   // [3,E]

  size_t off = 0;
  auto alloc = [&](size_t bytes) -> void* {
    void* p = (char*)d_ws + off;
    off += (bytes + 255) & ~(size_t)255;
    return p;
  };
  float* hlnA    = (float*)alloc((size_t)n * 64 * 4);
  float* hlnB    = (float*)alloc((size_t)n * 64 * 4);
  float* r       = (float*)alloc((size_t)n * 32 * 4);
  float* keep_i  = (float*)alloc((size_t)n * 4);
  float* keep_o  = (float*)alloc((size_t)n * 4);
  int*   deg     = (int*)alloc((size_t)n * 4);
  int*   row_ptr = (int*)alloc((size_t)(n + 1) * 4);
  int*   cursor  = (int*)alloc((size_t)n * 4);
  int*   bsum    = (int*)alloc(256 * 4);
  int*   bpref   = (int*)alloc(256 * 4);
  ull*   ce      = (ull*)alloc((size_t)e * 8);
  if (off > ws_size) return;  // ws too small: bail loudly

  const int nb = (n + 255) / 256;  // 196

  hipMemsetAsync(deg, 0, (size_t)n * 4, stream);
  k_count<<<(e + 255) / 256, 256, 0, stream>>>(dst, deg, e);
  k_bsum<<<nb, 256, 0, stream>>>(deg, bsum, n);
  k_bscan<<<1, 256, 0, stream>>>(bsum, bpref, nb, row_ptr, n);
  k_prefix<<<nb, 256, 0, stream>>>(deg, bpref, row_ptr, cursor, n);
  k_fill<<<(e + 255) / 256, 256, 0, stream>>>(src, dst, cursor, ce, e);

  const int g4 = n / 4;   // 12500 (N%4==0)
  const int g8 = n / 8;   // 6250  (N%8==0)

  k_enc_ln<<<g4, 256, 0, stream>>>(x, W_enc, b_enc, ln_g, ln_b, hlnA);

  float* hln = hlnA;
  float* hln_next = hlnB;
  for (int l = 0; l < 3; l++) {
    TF2 kin  = tf2x32(0u, 1234u, 0u, (unsigned)(2 * l));      // fold_in(key(1234), 2l)
    TF2 kout = tf2x32(0u, 1234u, 0u, (unsigned)(2 * l + 1));  // fold_in(key(1234), 2l+1)

    k_aggA<<<g4, 256, 0, stream>>>(hln, row_ptr, ce, in_W1, in_b1, out_W1, out_b1, r);
    k_aggB<<<g8, 256, 0, stream>>>(r, row_ptr, ce, in_W2, in_b2, out_W2, out_b2,
                                   keep_i, keep_o, kin.a, kin.b, kout.a, kout.b);
    if (l < 2) {
      k_aggC<true><<<g4, 256, 0, stream>>>(hln, row_ptr, ce, keep_i, keep_o,
                                           out_ew + (size_t)l * e,
                                           env_W + (size_t)l * 128 * 64,
                                           env_b + (size_t)l * 64, ln_g, ln_b, hln_next);
    } else {
      k_aggC<false><<<g4, 256, 0, stream>>>(hln, row_ptr, ce, keep_i, keep_o,
                                            out_ew + (size_t)l * e,
                                            env_W + (size_t)l * 128 * 64,
                                            env_b + (size_t)l * 64, ln_g, ln_b, hln_next);
    }
    float* tmp = hln; hln = hln_next; hln_next = tmp;
  }

  k_dec<<<g8, 256, 0, stream>>>(hln, W_dec, b_dec, out_h);
}